// Round 5
// baseline (5751.846 us; speedup 1.0000x reference)
//
#include <hip/hip_runtime.h>
#include <stdint.h>

// CharRNN MI355X — persistent dataflow-RNN, all-register K-loop edition.
//   K1 k_prep : proj[v][h] = embedding[v,:] @ W_ih + b_h  (VOCAB=64 table)
//   K2 k_rnn  : persistent 128 blocks (<=1/CU). Block (gi,gj): batch rows
//               gi*64..+64 (wave w owns 16), hidden cols gj*32..+32.
//               W_hh B-frags live in 256 VGPRs/wave; A-frags stream straight
//               from the coherent ring into registers (pipelined, chunk=8).
//               Per-step sync: __syncthreads (drain) + per-block flag store;
//               consumers poll 32 flags lane-parallel with __ballot.
//               Skew between blocks provably <=1 step -> 32-slot ring safe.
//               Every 16 steps: inline logits (W_ho bf16 frag-order in LDS).
// d_ws: proj f32 @0 (256KB) | flags @262144 (16KB) | ring bf16 @1MB (16MB)

#define BATCH 256
#define SEQ   512
#define HID   1024
#define VOC   64
#define EMB   256
#define FINAL_OFF (BATCH * SEQ * VOC)   // 8388608
#define NSLOT 32

typedef __attribute__((ext_vector_type(8))) short short8;
typedef __attribute__((ext_vector_type(4))) float f32x4;
typedef unsigned long long u64;

__device__ inline unsigned short f2bf(float f) {
  union { float f; unsigned u; } v; v.f = f;
  unsigned u = v.u;
  return (unsigned short)((u + 0x7FFFu + ((u >> 16) & 1u)) >> 16);  // RNE
}
__device__ inline u64 cload64(const void* p) {
  return __hip_atomic_load((const u64*)p, __ATOMIC_RELAXED,
                           __HIP_MEMORY_SCOPE_AGENT);
}
__device__ inline unsigned cload32(const void* p) {
  return __hip_atomic_load((const unsigned*)p, __ATOMIC_RELAXED,
                           __HIP_MEMORY_SCOPE_AGENT);
}
__device__ inline void cstore32(void* p, unsigned v) {
  __hip_atomic_store((unsigned*)p, v, __ATOMIC_RELAXED,
                     __HIP_MEMORY_SCOPE_AGENT);
}
__device__ inline short8 comb(u64 lo, u64 hi) {
  union { u64 d[2]; short8 s; } c; c.d[0] = lo; c.d[1] = hi; return c.s;
}
// all-lanes-parallel wait until the 32 flags at fb reach target
__device__ inline void poll_flags(const unsigned* fb, unsigned target, int lane) {
  int guard = 0;
  for (;;) {
    unsigned f = cload32(fb + (lane & 31));
    if (__ballot(f >= target) == ~0ull) break;
    __builtin_amdgcn_s_sleep(1);
    if (++guard > (1 << 15)) break;      // bailout: wrong answer beats a hang
  }
}

// ---------------- K1: projection table -------------------------------------
__global__ __launch_bounds__(256) void k_prep(const float* __restrict__ emb,
                                              const float* __restrict__ Wih,
                                              const float* __restrict__ bh,
                                              float* __restrict__ proj) {
  __shared__ float es[EMB];
  const int v = blockIdx.x >> 2;
  const int p = blockIdx.x & 3;
  const int tid = threadIdx.x;
  es[tid] = emb[v * EMB + tid];
  __syncthreads();
  const int h = p * 256 + tid;
  float acc = bh[h];
  for (int e = 0; e < EMB; ++e) acc += es[e] * Wih[e * HID + h];
  proj[v * HID + h] = acc;
}

// ---------------- K2: persistent recurrence + inline logits ----------------
// LDS: wlds (W_ho frag-order bf16) 131072 | p_lds 8192  => 139264
__global__ __launch_bounds__(256, 1) void k_rnn(
    const int* __restrict__ x, const float* __restrict__ Whh,
    const float* __restrict__ proj, const float* __restrict__ Who,
    const float* __restrict__ bo, unsigned short* __restrict__ ring,
    unsigned* __restrict__ flags, float* __restrict__ out,
    float* __restrict__ final_out) {
  extern __shared__ char smem[];
  unsigned short* wlds  = (unsigned short*)smem;        // 131072
  float*          p_lds = (float*)(smem + 131072);      // 8192

  const int tid = threadIdx.x, bid = blockIdx.x;
  const int gi = bid >> 5, gj = bid & 31;               // row-group / col-slice
  const int w = tid >> 6, lane = tid & 63;
  const int l15 = lane & 15, q = lane >> 4;
  const int rowA = gi * 64 + w * 16;                    // this wave's 16 rows
  const int colb = gj * 32;

  // W_ho -> LDS bf16 fragment order [kb][q][n][j]   (once)
  for (int it = 0; it < 256; ++it) {
    int u = it * 256 + tid;
    int j = u & 7, n = (u >> 3) & 63, qq = (u >> 9) & 3, kb = u >> 11;
    wlds[((kb * 4 + qq) * 64 + n) * 8 + j] = f2bf(Who[(kb * 32 + qq * 8 + j) * VOC + n]);
  }
  // proj slice [64 voc][32 local cols] -> LDS f32    (once)
  for (int it = 0; it < 8; ++it) {
    int u = it * 256 + tid;
    p_lds[u] = proj[(u >> 5) * HID + colb + (u & 31)];
  }
  // W_hh B-fragments -> 256 VGPRs/wave (2 n-tiles x 32 kb)  (once)
  short8 bhh[64];
  #pragma unroll
  for (int kb = 0; kb < 32; ++kb)
    #pragma unroll
    for (int nt = 0; nt < 2; ++nt) {
      short8 v8;
      #pragma unroll
      for (int j = 0; j < 8; ++j)
        v8[j] = (short)f2bf(Whh[(kb * 32 + q * 8 + j) * HID + colb + nt * 16 + l15]);
      bhh[kb * 2 + nt] = v8;
    }
  __syncthreads();

  for (int t = 0; t < SEQ; ++t) {
    f32x4 acc0 = {0.f, 0.f, 0.f, 0.f}, acc1 = {0.f, 0.f, 0.f, 0.f};
    // 1) consume h_{t-1}: wait flags, stream A-frags global->reg->MFMA
    if (t > 0) {
      const unsigned* fb = flags + ((t - 1) & (NSLOT - 1)) * 128 + gi * 32;
      poll_flags(fb, (unsigned)t, lane);
      const unsigned short* sp =
          ring + (size_t)((t - 1) & (NSLOT - 1)) * (BATCH * HID) +
          (size_t)(rowA + l15) * HID + q * 8;
      u64 lo[2][8], hi[2][8];
      #pragma unroll
      for (int j = 0; j < 8; ++j) {
        lo[0][j] = cload64(sp + j * 32);
        hi[0][j] = cload64(sp + j * 32 + 4);
      }
      #pragma unroll
      for (int c = 0; c < 4; ++c) {
        int cur = c & 1;
        if (c < 3) {
          #pragma unroll
          for (int j = 0; j < 8; ++j) {
            lo[cur ^ 1][j] = cload64(sp + ((c + 1) * 8 + j) * 32);
            hi[cur ^ 1][j] = cload64(sp + ((c + 1) * 8 + j) * 32 + 4);
          }
        }
        #pragma unroll
        for (int j = 0; j < 8; ++j) {
          short8 af = comb(lo[cur][j], hi[cur][j]);
          acc0 = __builtin_amdgcn_mfma_f32_16x16x32_bf16(af, bhh[(c * 8 + j) * 2], acc0, 0, 0, 0);
          acc1 = __builtin_amdgcn_mfma_f32_16x16x32_bf16(af, bhh[(c * 8 + j) * 2 + 1], acc1, 0, 0, 0);
        }
      }
    }
    // 2) epilogue: h_t = tanh(proj[x_t] + acc) -> coherent packed stores
    unsigned short* st = ring + (size_t)(t & (NSLOT - 1)) * (BATCH * HID);
    float hv0[4], hv1[4];
    #pragma unroll
    for (int r = 0; r < 4; ++r) {
      int row = rowA + q * 4 + r;                       // D row = q*4+r
      int xv = x[row * SEQ + t];
      hv0[r] = tanhf(p_lds[xv * 32 + l15] + acc0[r]);
      hv1[r] = tanhf(p_lds[xv * 32 + 16 + l15] + acc1[r]);
      if (t == SEQ - 1) {
        final_out[row * HID + colb + l15]      = hv0[r];
        final_out[row * HID + colb + 16 + l15] = hv1[r];
      }
    }
    #pragma unroll
    for (int r = 0; r < 4; ++r) {
      unsigned m0 = f2bf(hv0[r]), m1 = f2bf(hv1[r]);
      unsigned o0 = (unsigned)__shfl_xor((int)m0, 1);
      unsigned o1 = (unsigned)__shfl_xor((int)m1, 1);
      if (!(l15 & 1)) {
        int row = rowA + q * 4 + r;
        cstore32(st + (size_t)row * HID + colb + l15,      m0 | (o0 << 16));
        cstore32(st + (size_t)row * HID + colb + 16 + l15, m1 | (o1 << 16));
      }
    }
    // 3) drain (syncthreads' vmcnt(0)) then publish this block's flag
    __syncthreads();
    if (tid == 0)
      cstore32(flags + (t & (NSLOT - 1)) * 128 + gi * 32 + gj, (unsigned)(t + 1));
    // 4) inline logits every 16 steps: block = 32 rows x 1 tsel x 64 voc
    if ((t & 15) == 15) {
      int tsel = t - 15 + (gj >> 1);
      int rl0  = gi * 64 + (gj & 1) * 32 + (w & 1) * 16;
      int np   = w >> 1;                                // n-tile pair: cols np*32..+32
      const unsigned* fb2 = flags + (tsel & (NSLOT - 1)) * 128 + gi * 32;
      poll_flags(fb2, (unsigned)(tsel + 1), lane);
      const unsigned short* ap =
          ring + (size_t)(tsel & (NSLOT - 1)) * (BATCH * HID) +
          (size_t)(rl0 + l15) * HID + q * 8;
      f32x4 lc0 = {0.f, 0.f, 0.f, 0.f}, lc1 = {0.f, 0.f, 0.f, 0.f};
      #pragma unroll
      for (int c = 0; c < 4; ++c) {
        u64 alo[8], ahi[8];
        #pragma unroll
        for (int j = 0; j < 8; ++j) {
          alo[j] = cload64(ap + (c * 8 + j) * 32);
          ahi[j] = cload64(ap + (c * 8 + j) * 32 + 4);
        }
        #pragma unroll
        for (int j = 0; j < 8; ++j) {
          int kb = c * 8 + j;
          short8 af = comb(alo[j], ahi[j]);
          short8 b0 = *(const short8*)(wlds + ((kb * 4 + q) * 64 + np * 32 + l15) * 8);
          short8 b1 = *(const short8*)(wlds + ((kb * 4 + q) * 64 + np * 32 + 16 + l15) * 8);
          lc0 = __builtin_amdgcn_mfma_f32_16x16x32_bf16(af, b0, lc0, 0, 0, 0);
          lc1 = __builtin_amdgcn_mfma_f32_16x16x32_bf16(af, b1, lc1, 0, 0, 0);
        }
      }
      float b0 = bo[np * 32 + l15], b1 = bo[np * 32 + 16 + l15];
      #pragma unroll
      for (int r = 0; r < 4; ++r) {
        size_t rowoff = ((size_t)(rl0 + q * 4 + r) * SEQ + tsel) * VOC;
        out[rowoff + np * 32 + l15]      = lc0[r] + b0;
        out[rowoff + np * 32 + 16 + l15] = lc1[r] + b1;
      }
    }
  }
}

// ---------------- launch ----------------------------------------------------
extern "C" void kernel_launch(void* const* d_in, const int* in_sizes, int n_in,
                              void* d_out, int out_size, void* d_ws, size_t ws_size,
                              hipStream_t stream) {
  const int*   x   = (const int*)d_in[0];
  const float* emb = (const float*)d_in[1];
  const float* Wih = (const float*)d_in[2];
  const float* Whh = (const float*)d_in[3];
  const float* bh  = (const float*)d_in[4];
  const float* Who = (const float*)d_in[5];
  const float* bo  = (const float*)d_in[6];
  float* out = (float*)d_out;

  char* ws = (char*)d_ws;
  float*          proj  = (float*)ws;                        // 262144 B
  unsigned*       flags = (unsigned*)(ws + 262144);          // 16384 B
  unsigned short* ring  = (unsigned short*)(ws + (1 << 20)); // 16 MiB

  size_t need = (size_t)(1 << 20) + (size_t)NSLOT * BATCH * HID * 2;
  if (ws_size < need) return;  // diagnostic fail instead of a fault

  (void)hipFuncSetAttribute(reinterpret_cast<const void*>(k_rnn),
                            hipFuncAttributeMaxDynamicSharedMemorySize, 139264);

  k_prep<<<256, 256, 0, stream>>>(emb, Wih, bh, proj);
  hipMemsetAsync(flags, 0, 16384, stream);
  k_rnn<<<128, 256, 139264, stream>>>(x, Whh, proj, Who, bo, ring, flags,
                                      out, out + FINAL_OFF);
}

// Round 6
// 2343.439 us; speedup vs baseline: 2.4544x; 2.4544x over previous
//
#include <hip/hip_runtime.h>
#include <stdint.h>

// CharRNN MI355X — persistent-RNN, parallel-flag-barrier edition.
//   K1 k_prep : proj[v][h] = embedding[v,:] @ W_ih + b_h  (VOCAB=64 table)
//   K2 k_rnn  : persistent 256 blocks (1/CU). Block (gi,gj): batch rows
//               gi*32..+32, hidden cols gj*32..+32. W_hh slice bf16 in LDS
//               (132 VGPR — round 5's W_hh-in-VGPR spilled at 192/256).
//               Cross-block h exchange via relaxed AGENT-scope atomics
//               (per-access coherent; no cache-maintenance fences).
//               Sync: __syncthreads drain -> per-block flag store (own 128B
//               line, parallel at mall) -> lane-parallel 32-flag poll+ballot.
//               (Round 4's 32x atomicAdd on one line serialized ~2us/step.)
//               Every 16 steps: inline logits MFMA -> d_out. 32-slot ring.
// d_ws: proj f32 @0 (256KB) | flags @262144 (32KB) | ring bf16 @1MB (16MB)

#define BATCH 256
#define SEQ   512
#define HID   1024
#define VOC   64
#define EMB   256
#define FINAL_OFF (BATCH * SEQ * VOC)   // 8388608
#define NSLOT 32

typedef __attribute__((ext_vector_type(8))) short short8;
typedef __attribute__((ext_vector_type(4))) float f32x4;
typedef unsigned long long u64;

__device__ inline unsigned short f2bf(float f) {
  union { float f; unsigned u; } v; v.f = f;
  unsigned u = v.u;
  return (unsigned short)((u + 0x7FFFu + ((u >> 16) & 1u)) >> 16);  // RNE
}
__device__ inline u64 cload64(const void* p) {
  return __hip_atomic_load((const u64*)p, __ATOMIC_RELAXED,
                           __HIP_MEMORY_SCOPE_AGENT);
}
__device__ inline unsigned cload32(const void* p) {
  return __hip_atomic_load((const unsigned*)p, __ATOMIC_RELAXED,
                           __HIP_MEMORY_SCOPE_AGENT);
}
__device__ inline void cstore32(void* p, unsigned v) {
  __hip_atomic_store((unsigned*)p, v, __ATOMIC_RELAXED,
                     __HIP_MEMORY_SCOPE_AGENT);
}

// Wait until all 32 blocks of group gi have published step t (flag >= t+1).
// Each block's flag lives in its own 128B line; 32 lanes poll in parallel.
__device__ inline void poll_group(const unsigned* flags, int gi, int t, int lane) {
  const unsigned* fp = flags + (size_t)(gi * 32 + (lane & 31)) * 32 + (t & (NSLOT - 1));
  unsigned target = (unsigned)(t + 1);
  int guard = 0;
  for (;;) {
    unsigned f = cload32(fp);
    if (__ballot(f >= target) == ~0ull) break;
    __builtin_amdgcn_s_sleep(1);
    if (++guard > (1 << 15)) break;      // bailout: wrong answer beats a hang
  }
}

// ---------------- K1: projection table -------------------------------------
__global__ __launch_bounds__(256) void k_prep(const float* __restrict__ emb,
                                              const float* __restrict__ Wih,
                                              const float* __restrict__ bh,
                                              float* __restrict__ proj) {
  __shared__ float es[EMB];
  const int v = blockIdx.x >> 2;
  const int p = blockIdx.x & 3;
  const int tid = threadIdx.x;
  es[tid] = emb[v * EMB + tid];
  __syncthreads();
  const int h = p * 256 + tid;
  float acc = bh[h];
  for (int e = 0; e < EMB; ++e) acc += es[e] * Wih[e * HID + h];
  proj[v * HID + h] = acc;
}

// ---------------- K2: persistent recurrence + inline logits ----------------
// LDS: w_lds 65536 | h_lds 66048 (32 rows x 2064B) | p_lds 8192 | xs 128
__global__ __launch_bounds__(256, 1) void k_rnn(
    const int* __restrict__ x, const float* __restrict__ Whh,
    const float* __restrict__ proj, const float* __restrict__ Who,
    const float* __restrict__ bo, unsigned short* __restrict__ ring,
    unsigned* __restrict__ flags, float* __restrict__ out,
    float* __restrict__ final_out) {
  extern __shared__ char smem[];
  unsigned short* w_lds = (unsigned short*)smem;            // 65536
  char*           h_lds = smem + 65536;                     // 66048
  float*          p_lds = (float*)(smem + 131584);          // 8192
  int*            xs    = (int*)(smem + 139776);            // 128

  const int tid = threadIdx.x, bid = blockIdx.x;
  const int gi = bid & 7, gj = bid >> 3;                    // group / col-slice
  const int row0 = gi * 32;
  const int lane = tid & 63, wv = tid >> 6;
  const int mt = wv & 1, nt = wv >> 1;                      // recurrence tiles
  const int l15 = lane & 15, q = lane >> 4;

  // W_hh column slice -> LDS bf16 B-fragment order (once).
  for (int it = 0; it < 128; ++it) {
    int u = it * 256 + tid;
    int n = u & 31, j8 = (u >> 5) & 7, qq = (u >> 8) & 3, kb = u >> 10;
    w_lds[((kb * 4 + qq) * 32 + n) * 8 + j8] =
        f2bf(Whh[(kb * 32 + qq * 8 + j8) * HID + gj * 32 + n]);
  }
  // proj slice [64 vocab][32 cols] -> LDS f32 (once).
  for (int it = 0; it < 8; ++it) {
    int u = it * 256 + tid;
    p_lds[u] = proj[(u >> 5) * HID + gj * 32 + (u & 31)];
  }
  if (tid < 32) xs[tid] = x[(row0 + tid) * SEQ];
  // W_ho B-fragments for this wave's 16-voc tile.
  short8 wf[32];
  #pragma unroll
  for (int kb = 0; kb < 32; ++kb) {
    short8 v8;
    #pragma unroll
    for (int j = 0; j < 8; ++j)
      v8[j] = (short)f2bf(Who[(kb * 32 + q * 8 + j) * VOC + wv * 16 + l15]);
    wf[kb] = v8;
  }
  __syncthreads();

  const int hcol = gj * 32 + nt * 16 + l15;
  const char* abase = h_lds + (mt * 16 + l15) * 2064 + q * 16;
  const char* bbase = (const char*)w_lds + (q * 32 + nt * 16 + l15) * 16;
  const float bias = bo[wv * 16 + l15];
  unsigned* myflag = flags + (size_t)(gi * 32 + gj) * 32;

  for (int t = 0; t < SEQ; ++t) {
    // 1) recurrence MFMA: 32x32 tile = h_prev(32x1024) @ Whh_slice(1024x32)
    //    (h_lds staged at end of previous iteration; poll covered it)
    f32x4 a0 = {0.f, 0.f, 0.f, 0.f}, a1 = {0.f, 0.f, 0.f, 0.f};
    if (t > 0) {
      #pragma unroll 4
      for (int kb = 0; kb < 32; kb += 2) {
        short8 af0 = *(const short8*)(abase + kb * 64);
        short8 bf0 = *(const short8*)(bbase + kb * 2048);
        a0 = __builtin_amdgcn_mfma_f32_16x16x32_bf16(af0, bf0, a0, 0, 0, 0);
        short8 af1 = *(const short8*)(abase + kb * 64 + 64);
        short8 bf1 = *(const short8*)(bbase + kb * 2048 + 2048);
        a1 = __builtin_amdgcn_mfma_f32_16x16x32_bf16(af1, bf1, a1, 0, 0, 0);
      }
    }
    // 2) epilogue: h_t = tanh(proj[x_t] + acc); coherent packed stores
    unsigned short* slot = ring + (size_t)(t & (NSLOT - 1)) * (BATCH * HID);
    float hv[4];
    #pragma unroll
    for (int r = 0; r < 4; ++r) {
      int ml = mt * 16 + q * 4 + r;                         // D row = q*4+r
      hv[r] = tanhf(p_lds[xs[ml] * 32 + nt * 16 + l15] + a0[r] + a1[r]);
      if (t == SEQ - 1) final_out[(row0 + ml) * HID + hcol] = hv[r];
    }
    #pragma unroll
    for (int r = 0; r < 4; ++r) {
      unsigned myb = f2bf(hv[r]);
      unsigned oth = (unsigned)__shfl_xor((int)myb, 1);
      if ((l15 & 1) == 0) {
        int b = row0 + mt * 16 + q * 4 + r;
        cstore32(slot + (size_t)b * HID + hcol, myb | (oth << 16));
      }
    }
    // 3) drain all waves' stores, publish own flag, join group at step t
    __syncthreads();                      // vmcnt(0)+barrier = release
    if (tid == 0) cstore32(myflag + (t & (NSLOT - 1)), (unsigned)(t + 1));
    poll_group(flags, gi, t, lane);
    // 4) inline logits every 16 steps: block = 16 rows x 1 tsel x 64 voc
    if ((t & 15) == 15) {
      int tsel  = (t - 15) + (gj >> 1);                     // <= t, covered
      int rbase = row0 + (gj & 1) * 16;
      const unsigned short* hs =
          ring + (size_t)(tsel & (NSLOT - 1)) * (BATCH * HID) +
          (size_t)(rbase + l15) * HID;                      // A row base
      f32x4 lc = {0.f, 0.f, 0.f, 0.f};
      for (int g = 0; g < 4; ++g) {
        u64 hb[16];
        #pragma unroll
        for (int j = 0; j < 8; ++j) {
          const unsigned short* pk = hs + (g * 8 + j) * 32 + q * 8;
          hb[2 * j]     = cload64(pk);
          hb[2 * j + 1] = cload64(pk + 4);
        }
        #pragma unroll
        for (int j = 0; j < 8; ++j) {
          union { u64 d[2]; short8 s; } c;
          c.d[0] = hb[2 * j]; c.d[1] = hb[2 * j + 1];
          lc = __builtin_amdgcn_mfma_f32_16x16x32_bf16(c.s, wf[g * 8 + j],
                                                       lc, 0, 0, 0);
        }
      }
      #pragma unroll
      for (int rr = 0; rr < 4; ++rr) {
        int b = rbase + q * 4 + rr;
        out[((size_t)b * SEQ + tsel) * VOC + wv * 16 + l15] = lc[rr] + bias;
      }
    }
    // 5) restage h_t (32 rows x 1024, coherent 8B loads) -> h_lds
    if (t < SEQ - 1) {
      u64 tmp[32];
      #pragma unroll
      for (int rr = 0; rr < 32; ++rr)
        tmp[rr] = cload64(slot + (size_t)(row0 + rr) * HID + tid * 4);
      #pragma unroll
      for (int rr = 0; rr < 32; ++rr)
        *(u64*)(h_lds + rr * 2064 + tid * 8) = tmp[rr];
      if (tid < 32) xs[tid] = x[(row0 + tid) * SEQ + (t + 1)];
      __syncthreads();
    }
  }
}

// ---------------- launch ----------------------------------------------------
extern "C" void kernel_launch(void* const* d_in, const int* in_sizes, int n_in,
                              void* d_out, int out_size, void* d_ws, size_t ws_size,
                              hipStream_t stream) {
  const int*   x   = (const int*)d_in[0];
  const float* emb = (const float*)d_in[1];
  const float* Wih = (const float*)d_in[2];
  const float* Whh = (const float*)d_in[3];
  const float* bh  = (const float*)d_in[4];
  const float* Who = (const float*)d_in[5];
  const float* bo  = (const float*)d_in[6];
  float* out = (float*)d_out;

  char* ws = (char*)d_ws;
  float*          proj  = (float*)ws;                        // 262144 B
  unsigned*       flags = (unsigned*)(ws + 262144);          // 32768 B
  unsigned short* ring  = (unsigned short*)(ws + (1 << 20)); // 16 MiB

  size_t need = (size_t)(1 << 20) + (size_t)NSLOT * BATCH * HID * 2;
  if (ws_size < need) return;  // diagnostic fail instead of a fault

  (void)hipFuncSetAttribute(reinterpret_cast<const void*>(k_rnn),
                            hipFuncAttributeMaxDynamicSharedMemorySize, 139904);

  k_prep<<<256, 256, 0, stream>>>(emb, Wih, bh, proj);
  hipMemsetAsync(flags, 0, 32768, stream);
  k_rnn<<<256, 256, 139904, stream>>>(x, Whh, proj, Who, bo, ring, flags,
                                      out, out + FINAL_OFF);
}